// Round 14
// baseline (615.590 us; speedup 1.0000x reference)
//
#include <hip/hip_runtime.h>

#define NELEM 21600
#define KSEL 1000
#define MAXB 18
#define NT 1024
#define CAP 2048
#define NBIN 6144
#define NCHUNK 4
#define QC 8100                     // float4s per K1 block (32400/4)
#define QK 5400                     // keys per K2 block (21600/4)
#define NFULL 21                    // fallback: 21*1024 = 21504
#define NTAIL (NELEM - NFULL * NT)  // 96

typedef unsigned long long ull;

// monotone map: ascending uint key <-> ascending float
__device__ __forceinline__ unsigned fkey(float f) {
  unsigned u = __float_as_uint(f);
  return (u & 0x80000000u) ? ~u : (u | 0x80000000u);
}
__device__ __forceinline__ float unfkey(unsigned k) {
  unsigned u = (k & 0x80000000u) ? (k ^ 0x80000000u) : ~k;
  return __uint_as_float(u);
}

// ---------------- K1: full-chip float4 scan -> keys + chunk hists --------------
__global__ __launch_bounds__(NT) void k1_scan(
    const float* __restrict__ x, unsigned* __restrict__ gkeys,
    unsigned* __restrict__ ghist, unsigned* __restrict__ gcnt,
    unsigned* __restrict__ gflag) {
  const int blk = blockIdx.x;
  const int s = blk >> 2, c = blk & 3;
  const int t = threadIdx.x;
  const float4* xq = (const float4*)(x + (size_t)s * NELEM * 6);
  unsigned* gk = gkeys + (size_t)s * NELEM;

  __shared__ unsigned h[2048];
  h[2 * t] = 0u; h[2 * t + 1] = 0u;
  if (c == 0 && t == 0) { gcnt[s] = 0u; gflag[s] = 0u; }
  __syncthreads();

  const int base = c * QC;
  #pragma unroll
  for (int k = 0; k < 8; ++k) {
    int off = t + (k << 10);
    if (k < 7 || off < QC) {
      int g = base + off;
      float4 v = xq[g];
      int r = g % 3;
      if (r == 0) {
        unsigned key = fkey(v.x);
        gk[2 * (g / 3)] = key;
        atomicAdd(&h[key >> 21], 1u);
      } else if (r == 1) {
        unsigned key = fkey(v.z);
        gk[2 * (g / 3) + 1] = key;
        atomicAdd(&h[key >> 21], 1u);
      }
    }
  }
  __syncthreads();
  unsigned* gh = ghist + (size_t)blk * 2048;
  gh[2 * t] = h[2 * t];
  gh[2 * t + 1] = h[2 * t + 1];
}

// Wave-shuffle bucket select over hist[2048]. 16 waves x 128 buckets.
__device__ void select_bucket(const unsigned* hist, unsigned target,
                              volatile unsigned* chunkSuf,
                              unsigned* outB, unsigned* outCnt, unsigned* outAbove) {
  const int tid = threadIdx.x;
  const int w = tid >> 6, l = tid & 63;
  unsigned h1 = hist[w * 128 + 2 * l + 1];
  unsigned s = hist[w * 128 + 2 * l] + h1;
  #pragma unroll
  for (int d = 1; d < 64; d <<= 1) {
    unsigned t = __shfl_down(s, d);
    if (l + d < 64) s += t;
  }
  if (l == 0) chunkSuf[w] = s;
  __syncthreads();
  if (w == 0) {
    unsigned ct = (l < 16) ? chunkSuf[l] : 0u;
    unsigned cs = ct;
    #pragma unroll
    for (int d = 1; d < 16; d <<= 1) {
      unsigned t = __shfl_down(cs, d);
      if (l + d < 16) cs += t;
    }
    if (l < 16) chunkSuf[l] = cs - ct;
  }
  __syncthreads();
  unsigned base = chunkSuf[w];
  unsigned sufE = s + base;
  unsigned sN = __shfl_down(s, 1);
  unsigned sufN = ((l < 63) ? sN : 0u) + base;
  unsigned geOdd = sufN + h1;
  if (sufE >= target && geOdd < target) { *outB = w * 128u + 2u * l;     *outCnt = sufE;  *outAbove = geOdd; }
  if (geOdd >= target && sufN < target) { *outB = w * 128u + 2u * l + 1; *outCnt = geOdd; *outAbove = sufN;  }
  __syncthreads();
}

// ---------------- K2: full-chip threshold + compact (4 blocks/sample) ----------
__global__ __launch_bounds__(NT) void k2_compact(
    const unsigned* __restrict__ gkeys, const unsigned* __restrict__ ghist,
    ull* __restrict__ gselPk, unsigned* __restrict__ gcnt,
    unsigned* __restrict__ gflag, unsigned* __restrict__ gtb) {
  const int blk = blockIdx.x;
  const int s = blk >> 2, q = blk & 3;
  const int tid = threadIdx.x;

  __shared__ unsigned hist[2048];
  __shared__ unsigned chunkSuf[16];
  __shared__ ull lbuf[CAP];
  __shared__ unsigned lcnt, gbase;
  __shared__ unsigned sB, sCnt, sAbove;

  {
    unsigned h0 = 0, h1 = 0;
    #pragma unroll
    for (int c = 0; c < NCHUNK; ++c) {
      const unsigned* gh = ghist + (size_t)(s * NCHUNK + c) * 2048;
      h0 += gh[2 * tid];
      h1 += gh[2 * tid + 1];
    }
    hist[2 * tid] = h0; hist[2 * tid + 1] = h1;
  }
  if (tid == 0) lcnt = 0u;
  __syncthreads();
  select_bucket(hist, KSEL, chunkSuf, &sB, &sCnt, &sAbove);

  if (sCnt > (unsigned)CAP) {                 // astronomically rare tie storm
    if (tid == 0 && q == 0) gflag[s] = 1u;
    return;
  }
  const unsigned TB = sB << 21;
  if (tid == 0 && q == 0) gtb[s] = TB;
  const unsigned* ks = gkeys + (size_t)s * NELEM + q * QK;
  const int lw = tid & 63;
  #pragma unroll
  for (int it = 0; it < 6; ++it) {
    int i = tid + (it << 10);
    bool pred = false;
    unsigned k = 0u;
    if (i < QK) { k = ks[i]; pred = (k >= TB); }
    ull mask = __ballot(pred);
    if (mask) {
      int leader = __builtin_ctzll(mask);
      unsigned tot = (unsigned)__popcll(mask);
      unsigned bp = 0;
      if (lw == leader) bp = atomicAdd(&lcnt, tot);
      bp = __shfl(bp, leader);
      if (pred) {
        unsigned p = bp + (unsigned)__popcll(mask & ((1ull << lw) - 1ull));
        unsigned idx = (unsigned)(q * QK + i);
        lbuf[p] = ((ull)k << 32) | (unsigned)(~idx);
      }
    }
  }
  __syncthreads();
  if (tid == 0) gbase = atomicAdd(&gcnt[s], lcnt);
  __syncthreads();
  ull* gs = gselPk + (size_t)s * CAP;
  const unsigned n = lcnt, b0 = gbase;
  for (unsigned i = tid; i < n; i += NT) gs[b0 + i] = lbuf[i];
}

// ---------------- K3: counting sort + decode + NMS + output --------------------
__global__ __launch_bounds__(NT) void k3_final(
    const float* __restrict__ x, const float* __restrict__ anch,
    const unsigned* __restrict__ gkeys, const unsigned* __restrict__ ghist,
    const ull* __restrict__ gselPk, const unsigned* __restrict__ gcnt,
    const unsigned* __restrict__ gflag, const unsigned* __restrict__ gtb,
    float* __restrict__ out) {
  const int s = blockIdx.x;
  const int tid = threadIdx.x;
  const float* xb = x + (size_t)s * NELEM * 6;

  __shared__ ull pkraw[CAP];
  __shared__ ull sorted[CAP];
  __shared__ unsigned hist[NBIN + 2];          // also reused by fallback select
  __shared__ unsigned short orig16[NBIN + 2];
  __shared__ float px1[1088], py1[1088], px2[1088], py2[1088];
  __shared__ unsigned chunkSuf[16];
  __shared__ unsigned sB, sCnt, sAbove;
  __shared__ unsigned cntsh;
  __shared__ int keptRank[MAXB];
  __shared__ int numKept;

  unsigned n, TB;
  if (gflag[s] == 0u) {
    // ---- fast path: coalesced load of pre-compacted candidates ----
    n = gcnt[s]; if (n > CAP) n = CAP;
    TB = gtb[s];
    const ull* gs = gselPk + (size_t)s * CAP;
    for (unsigned i = tid; i < n; i += NT) pkraw[i] = gs[i];
    // hist zero runs below (before barrier)
  } else {
    // ---- rare fallback: in-block exact select (22-bit refine) + compact ----
    const unsigned* ks = gkeys + (size_t)s * NELEM;
    unsigned kv[NFULL];
    #pragma unroll
    for (int u = 0; u < NFULL; ++u) kv[u] = ks[tid + (u << 10)];
    unsigned ktail = 0u;
    const bool hastail = tid < NTAIL;
    if (hastail) ktail = ks[tid + NFULL * NT];
    {
      unsigned h0 = 0, h1 = 0;
      #pragma unroll
      for (int c = 0; c < NCHUNK; ++c) {
        const unsigned* gh = ghist + (size_t)(s * NCHUNK + c) * 2048;
        h0 += gh[2 * tid];
        h1 += gh[2 * tid + 1];
      }
      hist[2 * tid] = h0; hist[2 * tid + 1] = h1;
    }
    __syncthreads();
    select_bucket(hist, KSEL, chunkSuf, &sB, &sCnt, &sAbove);
    const unsigned b1 = sB, above1 = sAbove;
    hist[2 * tid] = 0u; hist[2 * tid + 1] = 0u;
    __syncthreads();
    #pragma unroll
    for (int u = 0; u < NFULL; ++u)
      if ((kv[u] >> 21) == b1) atomicAdd(&hist[(kv[u] >> 10) & 0x7FFu], 1u);
    if (hastail && (ktail >> 21) == b1) atomicAdd(&hist[(ktail >> 10) & 0x7FFu], 1u);
    __syncthreads();
    select_bucket(hist, KSEL - above1, chunkSuf, &sB, &sCnt, &sAbove);
    TB = (b1 << 21) | (sB << 10);
    if (tid == 0) cntsh = 0u;
    __syncthreads();
    const int lw = tid & 63;
    #pragma unroll
    for (int u = 0; u < NFULL; ++u) {
      bool pred = kv[u] >= TB;
      ull mask = __ballot(pred);
      if (mask) {
        int leader = __builtin_ctzll(mask);
        unsigned total = (unsigned)__popcll(mask);
        unsigned basep = 0;
        if (lw == leader) basep = atomicAdd(&cntsh, total);
        basep = __shfl(basep, leader);
        if (pred) {
          unsigned p = basep + (unsigned)__popcll(mask & ((1ull << lw) - 1ull));
          unsigned i = (unsigned)(tid + (u << 10));
          if (p < CAP) pkraw[p] = ((ull)kv[u] << 32) | (unsigned)(~i);
        }
      }
    }
    if (hastail && ktail >= TB) {
      unsigned p = atomicAdd(&cntsh, 1u);
      unsigned i = (unsigned)(tid + NFULL * NT);
      if (p < CAP) pkraw[p] = ((ull)ktail << 32) | (unsigned)(~i);
    }
    __syncthreads();
    n = (cntsh < CAP) ? cntsh : CAP;
  }

  // ---- counting sort: bin by (key - TB) >> 10, exact fixup per bin ----
  {
    // zero hist
    #pragma unroll
    for (int j = 0; j < 6; ++j) hist[tid * 6 + j] = 0u;
    if (tid == 0) { hist[NBIN] = 0u; hist[NBIN + 1] = 0u; }
    __syncthreads();
    // histogram (2 elems/thread)
    #pragma unroll
    for (int e0 = 0; e0 < 2; ++e0) {
      unsigned e = tid + (e0 << 10);
      if (e < n) {
        unsigned key = (unsigned)(pkraw[e] >> 32);
        unsigned bin = (key - TB) >> 10;
        if (bin > (NBIN - 1)) bin = NBIN - 1;
        atomicAdd(&hist[bin], 1u);
      }
    }
    __syncthreads();
    // suffix scan: suf[b] = sum_{b' >= b} cnt[b']
    unsigned c6[6];
    #pragma unroll
    for (int j = 0; j < 6; ++j) c6[j] = hist[tid * 6 + j];
    unsigned part = 0;
    #pragma unroll
    for (int j = 0; j < 6; ++j) part += c6[j];
    const int w = tid >> 6, l = tid & 63;
    unsigned ssum = part;
    #pragma unroll
    for (int d = 1; d < 64; d <<= 1) {
      unsigned t2 = __shfl_down(ssum, d);
      if (l + d < 64) ssum += t2;
    }
    if (l == 0) chunkSuf[w] = ssum;
    __syncthreads();
    if (w == 0) {
      unsigned ct = (l < 16) ? chunkSuf[l] : 0u;
      unsigned cs = ct;
      #pragma unroll
      for (int d = 1; d < 16; d <<= 1) {
        unsigned t2 = __shfl_down(cs, d);
        if (l + d < 16) cs += t2;
      }
      if (l < 16) chunkSuf[l] = cs - ct;   // sum over waves after w
    }
    __syncthreads();
    unsigned after = chunkSuf[w] + (ssum - part);  // elems in bins after mine
    unsigned run = after;
    unsigned suf6[6];
    #pragma unroll
    for (int j = 5; j >= 0; --j) { run += c6[j]; suf6[j] = run; }
    __syncthreads();                      // all reads of hist done; now overwrite
    #pragma unroll
    for (int j = 0; j < 6; ++j) {
      hist[tid * 6 + j] = suf6[j];
      orig16[tid * 6 + j] = (unsigned short)suf6[j];
    }
    if (tid == 0) { hist[NBIN] = 0u; orig16[NBIN] = 0; }
    __syncthreads();
    // scatter: bin b's counter slot is hist[b+1] (holds base(b) = suf[b+1])
    #pragma unroll
    for (int e0 = 0; e0 < 2; ++e0) {
      unsigned e = tid + (e0 << 10);
      if (e < n) {
        ull pk = pkraw[e];
        unsigned key = (unsigned)(pk >> 32);
        unsigned bin = (key - TB) >> 10;
        if (bin > (NBIN - 1)) bin = NBIN - 1;
        unsigned pos = atomicAdd(&hist[bin + 1], 1u);
        sorted[pos] = pk;
      }
    }
    __syncthreads();
    // fixup: insertion sort within each bin segment [orig16[b+1], orig16[b])
    #pragma unroll
    for (int b0 = 0; b0 < 6; ++b0) {
      int b = tid + (b0 << 10);
      if (b < NBIN) {
        int st = orig16[b + 1];
        int en = orig16[b];
        for (int i = st + 1; i < en; ++i) {
          ull v = sorted[i];
          int j = i - 1;
          while (j >= st && sorted[j] < v) { sorted[j + 1] = sorted[j]; --j; }
          sorted[j + 1] = v;
        }
      }
    }
    __syncthreads();
  }

  // ---- decode first 1000 into stride-17 scalar LDS arrays (conflict-free) ----
  if (tid < KSEL) {
    unsigned idx = ~(unsigned)sorted[tid];
    const float2* e2 = (const float2*)(xb + (size_t)idx * 6 + 2);
    float2 ra = e2[0], rb = e2[1];
    unsigned pp = (idx / 9u) % 60u;
    unsigned qq = idx / 540u;
    unsigned sr = idx % 9u;
    const float* ap = anch + (((pp * 40u + qq) * 9u + sr) * 4u);
    float ax = ap[0], ay = ap[1], aw = ap[2], ah = ap[3];
    float xc = ra.x * aw + ax;
    float yc = ra.y * ah + ay;
    float w = aw * expf(rb.x);
    float h = ah * expf(rb.y);
    int a = (tid >> 4) * 17 + (tid & 15);
    px1[a] = xc - 0.5f * w; px2[a] = xc + 0.5f * w;
    py1[a] = yc - 0.5f * h; py2[a] = yc + 0.5f * h;
  }
  __syncthreads();

  // ---- ballot-NMS on wave 0: coords from LDS, tiny register state ----
  if (tid < 64) {
    const int lane = tid;
    unsigned alive = 0u;
    #pragma unroll
    for (int ss = 0; ss < 16; ++ss) {
      int r = lane * 16 + ss;
      alive |= (r < KSEL ? 1u : 0u) << ss;
    }
    int nk = 0;
    while (nk < MAXB) {
      ull bal = __ballot(alive != 0u);
      if (!bal) break;
      int F = __builtin_ctzll(bal);
      int myss = (int)__builtin_ctz(alive | 0x10000u);
      int ssw = __shfl(myss, F);
      int m = F * 16 + ssw;
      if (lane == 0) keptRank[nk] = m;
      int am = (m >> 4) * 17 + (m & 15);
      float wx1 = px1[am], wy1 = py1[am], wx2 = px2[am], wy2 = py2[am];
      ++nk;
      if (nk >= MAXB) break;
      #pragma unroll
      for (int ss = 0; ss < 16; ++ss) {
        if (alive & (1u << ss)) {
          int a = lane * 17 + ss;
          float x1 = px1[a], y1 = py1[a], x2 = px2[a], y2 = py2[a];
          float iw = fmaxf(fminf(x2, wx2) - fmaxf(x1, wx1), 0.f);
          float ih = fmaxf(fminf(y2, wy2) - fmaxf(y1, wy1), 0.f);
          float ar = (x2 - x1) * (y2 - y1);
          if (iw * ih / ar > 0.5f) alive &= ~(1u << ss);  // winner self-clears
        }
      }
    }
    if (lane == 0) numKept = nk;
  }
  __syncthreads();

  // ---- output: kept rows then pad rows cand[j - n]; score from key bits ----
  const int nK = numKept;
  if (tid < MAXB) {
    int j = tid;
    int r = (j < nK) ? keptRank[j] : (j - nK);
    ull pk = sorted[r];
    unsigned idx = ~(unsigned)pk;
    float sc = unfkey((unsigned)(pk >> 32));
    const float2* e2 = (const float2*)(xb + (size_t)idx * 6 + 2);
    float2 ra = e2[0], rb = e2[1];
    unsigned pp = (idx / 9u) % 60u;
    unsigned qq = idx / 540u;
    unsigned sr = idx % 9u;
    const float* ap = anch + (((pp * 40u + qq) * 9u + sr) * 4u);
    float ax = ap[0], ay = ap[1], aw = ap[2], ah = ap[3];
    float xc = ra.x * aw + ax;
    float yc = ra.y * ah + ay;
    float w = aw * expf(rb.x);
    float h = ah * expf(rb.y);
    float* o = out + s * (MAXB * 5) + j * 5;
    o[0] = xc; o[1] = yc; o[2] = w; o[3] = h; o[4] = sc;
  }
}

extern "C" void kernel_launch(void* const* d_in, const int* in_sizes, int n_in,
                              void* d_out, int out_size, void* d_ws, size_t ws_size,
                              hipStream_t stream) {
  const float* x = (const float*)d_in[0];
  const float* anch = (const float*)d_in[1];
  float* out = (float*)d_out;
  const int B = in_sizes[0] / (NELEM * 6);
  ull* gselPk = (ull*)d_ws;                                 // B*2048 u64
  unsigned* ghist = (unsigned*)(gselPk + (size_t)B * CAP);  // B*4*2048 u32
  unsigned* gkeys = ghist + (size_t)B * NCHUNK * 2048;      // B*21600 u32
  unsigned* gcnt = gkeys + (size_t)B * NELEM;               // B u32
  unsigned* gflag = gcnt + B;                               // B u32
  unsigned* gtb = gflag + B;                                // B u32
  k1_scan<<<dim3(B * NCHUNK), dim3(NT), 0, stream>>>(x, gkeys, ghist, gcnt, gflag);
  k2_compact<<<dim3(B * NCHUNK), dim3(NT), 0, stream>>>(gkeys, ghist, gselPk, gcnt, gflag, gtb);
  k3_final<<<dim3(B), dim3(NT), 0, stream>>>(x, anch, gkeys, ghist, gselPk, gcnt, gflag, gtb, out);
}

// Round 15
// 62.280 us; speedup vs baseline: 9.8842x; 9.8842x over previous
//
#include <hip/hip_runtime.h>

#define NELEM 21600
#define KSEL 1000
#define MAXB 18
#define NT 1024
#define CAP 2048
#define NBIN 6144
#define BSHIFT 12                   // bin width 4096 key-units: 6144 bins = 25.2M span
#define NCHUNK 4
#define QC 8100                     // float4s per K1 block (32400/4)
#define QK 5400                     // keys per K2 block (21600/4)
#define NFULL 21                    // fallback: 21*1024 = 21504
#define NTAIL (NELEM - NFULL * NT)  // 96

typedef unsigned long long ull;

// monotone map: ascending uint key <-> ascending float
__device__ __forceinline__ unsigned fkey(float f) {
  unsigned u = __float_as_uint(f);
  return (u & 0x80000000u) ? ~u : (u | 0x80000000u);
}
__device__ __forceinline__ float unfkey(unsigned k) {
  unsigned u = (k & 0x80000000u) ? (k ^ 0x80000000u) : ~k;
  return __uint_as_float(u);
}

// ---------------- K1: full-chip float4 scan -> keys + chunk hists --------------
__global__ __launch_bounds__(NT) void k1_scan(
    const float* __restrict__ x, unsigned* __restrict__ gkeys,
    unsigned* __restrict__ ghist, unsigned* __restrict__ gcnt,
    unsigned* __restrict__ gflag) {
  const int blk = blockIdx.x;
  const int s = blk >> 2, c = blk & 3;
  const int t = threadIdx.x;
  const float4* xq = (const float4*)(x + (size_t)s * NELEM * 6);
  unsigned* gk = gkeys + (size_t)s * NELEM;

  __shared__ unsigned h[2048];
  h[2 * t] = 0u; h[2 * t + 1] = 0u;
  if (c == 0 && t == 0) { gcnt[s] = 0u; gflag[s] = 0u; }
  __syncthreads();

  const int base = c * QC;
  #pragma unroll
  for (int k = 0; k < 8; ++k) {
    int off = t + (k << 10);
    if (k < 7 || off < QC) {
      int g = base + off;
      float4 v = xq[g];
      int r = g % 3;
      if (r == 0) {
        unsigned key = fkey(v.x);
        gk[2 * (g / 3)] = key;
        atomicAdd(&h[key >> 21], 1u);
      } else if (r == 1) {
        unsigned key = fkey(v.z);
        gk[2 * (g / 3) + 1] = key;
        atomicAdd(&h[key >> 21], 1u);
      }
    }
  }
  __syncthreads();
  unsigned* gh = ghist + (size_t)blk * 2048;
  gh[2 * t] = h[2 * t];
  gh[2 * t + 1] = h[2 * t + 1];
}

// Wave-shuffle bucket select over hist[2048]. 16 waves x 128 buckets.
__device__ void select_bucket(const unsigned* hist, unsigned target,
                              volatile unsigned* chunkSuf,
                              unsigned* outB, unsigned* outCnt, unsigned* outAbove) {
  const int tid = threadIdx.x;
  const int w = tid >> 6, l = tid & 63;
  unsigned h1 = hist[w * 128 + 2 * l + 1];
  unsigned s = hist[w * 128 + 2 * l] + h1;
  #pragma unroll
  for (int d = 1; d < 64; d <<= 1) {
    unsigned t = __shfl_down(s, d);
    if (l + d < 64) s += t;
  }
  if (l == 0) chunkSuf[w] = s;
  __syncthreads();
  if (w == 0) {
    unsigned ct = (l < 16) ? chunkSuf[l] : 0u;
    unsigned cs = ct;
    #pragma unroll
    for (int d = 1; d < 16; d <<= 1) {
      unsigned t = __shfl_down(cs, d);
      if (l + d < 16) cs += t;
    }
    if (l < 16) chunkSuf[l] = cs - ct;
  }
  __syncthreads();
  unsigned base = chunkSuf[w];
  unsigned sufE = s + base;
  unsigned sN = __shfl_down(s, 1);
  unsigned sufN = ((l < 63) ? sN : 0u) + base;
  unsigned geOdd = sufN + h1;
  if (sufE >= target && geOdd < target) { *outB = w * 128u + 2u * l;     *outCnt = sufE;  *outAbove = geOdd; }
  if (geOdd >= target && sufN < target) { *outB = w * 128u + 2u * l + 1; *outCnt = geOdd; *outAbove = sufN;  }
  __syncthreads();
}

// ---------------- K2: full-chip threshold + compact (4 blocks/sample) ----------
__global__ __launch_bounds__(NT) void k2_compact(
    const unsigned* __restrict__ gkeys, const unsigned* __restrict__ ghist,
    ull* __restrict__ gselPk, unsigned* __restrict__ gcnt,
    unsigned* __restrict__ gflag, unsigned* __restrict__ gtb) {
  const int blk = blockIdx.x;
  const int s = blk >> 2, q = blk & 3;
  const int tid = threadIdx.x;

  __shared__ unsigned hist[2048];
  __shared__ unsigned chunkSuf[16];
  __shared__ ull lbuf[CAP];
  __shared__ unsigned lcnt, gbase;
  __shared__ unsigned sB, sCnt, sAbove;

  {
    unsigned h0 = 0, h1 = 0;
    #pragma unroll
    for (int c = 0; c < NCHUNK; ++c) {
      const unsigned* gh = ghist + (size_t)(s * NCHUNK + c) * 2048;
      h0 += gh[2 * tid];
      h1 += gh[2 * tid + 1];
    }
    hist[2 * tid] = h0; hist[2 * tid + 1] = h1;
  }
  if (tid == 0) lcnt = 0u;
  __syncthreads();
  select_bucket(hist, KSEL, chunkSuf, &sB, &sCnt, &sAbove);

  if (sCnt > (unsigned)CAP) {                 // astronomically rare tie storm
    if (tid == 0 && q == 0) gflag[s] = 1u;
    return;
  }
  const unsigned TB = sB << 21;
  if (tid == 0 && q == 0) gtb[s] = TB;
  const unsigned* ks = gkeys + (size_t)s * NELEM + q * QK;
  const int lw = tid & 63;
  #pragma unroll
  for (int it = 0; it < 6; ++it) {
    int i = tid + (it << 10);
    bool pred = false;
    unsigned k = 0u;
    if (i < QK) { k = ks[i]; pred = (k >= TB); }
    ull mask = __ballot(pred);
    if (mask) {
      int leader = __builtin_ctzll(mask);
      unsigned tot = (unsigned)__popcll(mask);
      unsigned bp = 0;
      if (lw == leader) bp = atomicAdd(&lcnt, tot);
      bp = __shfl(bp, leader);
      if (pred) {
        unsigned p = bp + (unsigned)__popcll(mask & ((1ull << lw) - 1ull));
        unsigned idx = (unsigned)(q * QK + i);
        lbuf[p] = ((ull)k << 32) | (unsigned)(~idx);
      }
    }
  }
  __syncthreads();
  if (tid == 0) gbase = atomicAdd(&gcnt[s], lcnt);
  __syncthreads();
  ull* gs = gselPk + (size_t)s * CAP;
  const unsigned n = lcnt, b0 = gbase;
  for (unsigned i = tid; i < n; i += NT) gs[b0 + i] = lbuf[i];
}

// ---------------- K3: counting sort + decode + NMS + output --------------------
__global__ __launch_bounds__(NT) void k3_final(
    const float* __restrict__ x, const float* __restrict__ anch,
    const unsigned* __restrict__ gkeys, const unsigned* __restrict__ ghist,
    const ull* __restrict__ gselPk, const unsigned* __restrict__ gcnt,
    const unsigned* __restrict__ gflag, const unsigned* __restrict__ gtb,
    float* __restrict__ out) {
  const int s = blockIdx.x;
  const int tid = threadIdx.x;
  const float* xb = x + (size_t)s * NELEM * 6;

  __shared__ ull pkraw[CAP];
  __shared__ ull sorted[CAP];
  __shared__ unsigned hist[NBIN + 2];          // also reused by fallback select
  __shared__ unsigned short orig16[NBIN + 2];
  __shared__ float px1[1088], py1[1088], px2[1088], py2[1088];
  __shared__ unsigned chunkSuf[16];
  __shared__ unsigned sB, sCnt, sAbove;
  __shared__ unsigned cntsh;
  __shared__ int keptRank[MAXB];
  __shared__ int numKept;

  unsigned n, TB;
  if (gflag[s] == 0u) {
    // ---- fast path: coalesced load of pre-compacted candidates ----
    n = gcnt[s]; if (n > CAP) n = CAP;
    TB = gtb[s];
    const ull* gs = gselPk + (size_t)s * CAP;
    for (unsigned i = tid; i < n; i += NT) pkraw[i] = gs[i];
  } else {
    // ---- rare fallback: in-block exact select (22-bit refine) + compact ----
    const unsigned* ks = gkeys + (size_t)s * NELEM;
    unsigned kv[NFULL];
    #pragma unroll
    for (int u = 0; u < NFULL; ++u) kv[u] = ks[tid + (u << 10)];
    unsigned ktail = 0u;
    const bool hastail = tid < NTAIL;
    if (hastail) ktail = ks[tid + NFULL * NT];
    {
      unsigned h0 = 0, h1 = 0;
      #pragma unroll
      for (int c = 0; c < NCHUNK; ++c) {
        const unsigned* gh = ghist + (size_t)(s * NCHUNK + c) * 2048;
        h0 += gh[2 * tid];
        h1 += gh[2 * tid + 1];
      }
      hist[2 * tid] = h0; hist[2 * tid + 1] = h1;
    }
    __syncthreads();
    select_bucket(hist, KSEL, chunkSuf, &sB, &sCnt, &sAbove);
    const unsigned b1 = sB, above1 = sAbove;
    hist[2 * tid] = 0u; hist[2 * tid + 1] = 0u;
    __syncthreads();
    #pragma unroll
    for (int u = 0; u < NFULL; ++u)
      if ((kv[u] >> 21) == b1) atomicAdd(&hist[(kv[u] >> 10) & 0x7FFu], 1u);
    if (hastail && (ktail >> 21) == b1) atomicAdd(&hist[(ktail >> 10) & 0x7FFu], 1u);
    __syncthreads();
    select_bucket(hist, KSEL - above1, chunkSuf, &sB, &sCnt, &sAbove);
    TB = (b1 << 21) | (sB << 10);
    if (tid == 0) cntsh = 0u;
    __syncthreads();
    const int lw = tid & 63;
    #pragma unroll
    for (int u = 0; u < NFULL; ++u) {
      bool pred = kv[u] >= TB;
      ull mask = __ballot(pred);
      if (mask) {
        int leader = __builtin_ctzll(mask);
        unsigned total = (unsigned)__popcll(mask);
        unsigned basep = 0;
        if (lw == leader) basep = atomicAdd(&cntsh, total);
        basep = __shfl(basep, leader);
        if (pred) {
          unsigned p = basep + (unsigned)__popcll(mask & ((1ull << lw) - 1ull));
          unsigned i = (unsigned)(tid + (u << 10));
          if (p < CAP) pkraw[p] = ((ull)kv[u] << 32) | (unsigned)(~i);
        }
      }
    }
    if (hastail && ktail >= TB) {
      unsigned p = atomicAdd(&cntsh, 1u);
      unsigned i = (unsigned)(tid + NFULL * NT);
      if (p < CAP) pkraw[p] = ((ull)ktail << 32) | (unsigned)(~i);
    }
    __syncthreads();
    n = (cntsh < CAP) ? cntsh : CAP;
  }

  // ---- counting sort: bin by (key - TB) >> BSHIFT, exact fixup per bin ----
  {
    // zero hist
    #pragma unroll
    for (int j = 0; j < 6; ++j) hist[tid * 6 + j] = 0u;
    if (tid == 0) { hist[NBIN] = 0u; hist[NBIN + 1] = 0u; }
    __syncthreads();
    // histogram (2 elems/thread)
    #pragma unroll
    for (int e0 = 0; e0 < 2; ++e0) {
      unsigned e = tid + (e0 << 10);
      if (e < n) {
        unsigned key = (unsigned)(pkraw[e] >> 32);
        unsigned bin = (key - TB) >> BSHIFT;
        if (bin > (NBIN - 1)) bin = NBIN - 1;
        atomicAdd(&hist[bin], 1u);
      }
    }
    __syncthreads();
    // suffix scan: suf[b] = sum_{b' >= b} cnt[b']
    unsigned c6[6];
    #pragma unroll
    for (int j = 0; j < 6; ++j) c6[j] = hist[tid * 6 + j];
    unsigned part = 0;
    #pragma unroll
    for (int j = 0; j < 6; ++j) part += c6[j];
    const int w = tid >> 6, l = tid & 63;
    unsigned ssum = part;
    #pragma unroll
    for (int d = 1; d < 64; d <<= 1) {
      unsigned t2 = __shfl_down(ssum, d);
      if (l + d < 64) ssum += t2;
    }
    if (l == 0) chunkSuf[w] = ssum;
    __syncthreads();
    if (w == 0) {
      unsigned ct = (l < 16) ? chunkSuf[l] : 0u;
      unsigned cs = ct;
      #pragma unroll
      for (int d = 1; d < 16; d <<= 1) {
        unsigned t2 = __shfl_down(cs, d);
        if (l + d < 16) cs += t2;
      }
      if (l < 16) chunkSuf[l] = cs - ct;   // sum over waves after w
    }
    __syncthreads();
    unsigned after = chunkSuf[w] + (ssum - part);  // elems in bins after mine
    unsigned run = after;
    unsigned suf6[6];
    #pragma unroll
    for (int j = 5; j >= 0; --j) { run += c6[j]; suf6[j] = run; }
    __syncthreads();                      // all reads of hist done; now overwrite
    #pragma unroll
    for (int j = 0; j < 6; ++j) {
      hist[tid * 6 + j] = suf6[j];
      orig16[tid * 6 + j] = (unsigned short)suf6[j];
    }
    if (tid == 0) { hist[NBIN] = 0u; orig16[NBIN] = 0; }
    __syncthreads();
    // scatter: bin b's counter slot is hist[b+1] (holds base(b) = suf(b+1))
    #pragma unroll
    for (int e0 = 0; e0 < 2; ++e0) {
      unsigned e = tid + (e0 << 10);
      if (e < n) {
        ull pk = pkraw[e];
        unsigned key = (unsigned)(pk >> 32);
        unsigned bin = (key - TB) >> BSHIFT;
        if (bin > (NBIN - 1)) bin = NBIN - 1;
        unsigned pos = atomicAdd(&hist[bin + 1], 1u);
        sorted[pos] = pk;
      }
    }
    __syncthreads();
    // fixup: insertion sort within each bin segment [orig16[b+1], orig16[b])
    #pragma unroll
    for (int b0 = 0; b0 < 6; ++b0) {
      int b = tid + (b0 << 10);
      if (b < NBIN) {
        int st = orig16[b + 1];
        int en = orig16[b];
        for (int i = st + 1; i < en; ++i) {
          ull v = sorted[i];
          int j = i - 1;
          while (j >= st && sorted[j] < v) { sorted[j + 1] = sorted[j]; --j; }
          sorted[j + 1] = v;
        }
      }
    }
    __syncthreads();
  }

  // ---- decode first 1000 into stride-17 scalar LDS arrays (conflict-free) ----
  if (tid < KSEL) {
    unsigned idx = ~(unsigned)sorted[tid];
    const float2* e2 = (const float2*)(xb + (size_t)idx * 6 + 2);
    float2 ra = e2[0], rb = e2[1];
    unsigned pp = (idx / 9u) % 60u;
    unsigned qq = idx / 540u;
    unsigned sr = idx % 9u;
    const float* ap = anch + (((pp * 40u + qq) * 9u + sr) * 4u);
    float ax = ap[0], ay = ap[1], aw = ap[2], ah = ap[3];
    float xc = ra.x * aw + ax;
    float yc = ra.y * ah + ay;
    float w = aw * expf(rb.x);
    float h = ah * expf(rb.y);
    int a = (tid >> 4) * 17 + (tid & 15);
    px1[a] = xc - 0.5f * w; px2[a] = xc + 0.5f * w;
    py1[a] = yc - 0.5f * h; py2[a] = yc + 0.5f * h;
  }
  __syncthreads();

  // ---- ballot-NMS on wave 0: coords from LDS, tiny register state ----
  if (tid < 64) {
    const int lane = tid;
    unsigned alive = 0u;
    #pragma unroll
    for (int ss = 0; ss < 16; ++ss) {
      int r = lane * 16 + ss;
      alive |= (r < KSEL ? 1u : 0u) << ss;
    }
    int nk = 0;
    while (nk < MAXB) {
      ull bal = __ballot(alive != 0u);
      if (!bal) break;
      int F = __builtin_ctzll(bal);
      int myss = (int)__builtin_ctz(alive | 0x10000u);
      int ssw = __shfl(myss, F);
      int m = F * 16 + ssw;
      if (lane == 0) keptRank[nk] = m;
      int am = (m >> 4) * 17 + (m & 15);
      float wx1 = px1[am], wy1 = py1[am], wx2 = px2[am], wy2 = py2[am];
      ++nk;
      if (nk >= MAXB) break;
      #pragma unroll
      for (int ss = 0; ss < 16; ++ss) {
        if (alive & (1u << ss)) {
          int a = lane * 17 + ss;
          float x1 = px1[a], y1 = py1[a], x2 = px2[a], y2 = py2[a];
          float iw = fmaxf(fminf(x2, wx2) - fmaxf(x1, wx1), 0.f);
          float ih = fmaxf(fminf(y2, wy2) - fmaxf(y1, wy1), 0.f);
          float ar = (x2 - x1) * (y2 - y1);
          if (iw * ih / ar > 0.5f) alive &= ~(1u << ss);  // winner self-clears
        }
      }
    }
    if (lane == 0) numKept = nk;
  }
  __syncthreads();

  // ---- output: kept rows then pad rows cand[j - n]; score from key bits ----
  const int nK = numKept;
  if (tid < MAXB) {
    int j = tid;
    int r = (j < nK) ? keptRank[j] : (j - nK);
    ull pk = sorted[r];
    unsigned idx = ~(unsigned)pk;
    float sc = unfkey((unsigned)(pk >> 32));
    const float2* e2 = (const float2*)(xb + (size_t)idx * 6 + 2);
    float2 ra = e2[0], rb = e2[1];
    unsigned pp = (idx / 9u) % 60u;
    unsigned qq = idx / 540u;
    unsigned sr = idx % 9u;
    const float* ap = anch + (((pp * 40u + qq) * 9u + sr) * 4u);
    float ax = ap[0], ay = ap[1], aw = ap[2], ah = ap[3];
    float xc = ra.x * aw + ax;
    float yc = ra.y * ah + ay;
    float w = aw * expf(rb.x);
    float h = ah * expf(rb.y);
    float* o = out + s * (MAXB * 5) + j * 5;
    o[0] = xc; o[1] = yc; o[2] = w; o[3] = h; o[4] = sc;
  }
}

extern "C" void kernel_launch(void* const* d_in, const int* in_sizes, int n_in,
                              void* d_out, int out_size, void* d_ws, size_t ws_size,
                              hipStream_t stream) {
  const float* x = (const float*)d_in[0];
  const float* anch = (const float*)d_in[1];
  float* out = (float*)d_out;
  const int B = in_sizes[0] / (NELEM * 6);
  ull* gselPk = (ull*)d_ws;                                 // B*2048 u64
  unsigned* ghist = (unsigned*)(gselPk + (size_t)B * CAP);  // B*4*2048 u32
  unsigned* gkeys = ghist + (size_t)B * NCHUNK * 2048;      // B*21600 u32
  unsigned* gcnt = gkeys + (size_t)B * NELEM;               // B u32
  unsigned* gflag = gcnt + B;                               // B u32
  unsigned* gtb = gflag + B;                                // B u32
  k1_scan<<<dim3(B * NCHUNK), dim3(NT), 0, stream>>>(x, gkeys, ghist, gcnt, gflag);
  k2_compact<<<dim3(B * NCHUNK), dim3(NT), 0, stream>>>(gkeys, ghist, gselPk, gcnt, gflag, gtb);
  k3_final<<<dim3(B), dim3(NT), 0, stream>>>(x, anch, gkeys, ghist, gselPk, gcnt, gflag, gtb, out);
}

// Round 16
// 60.721 us; speedup vs baseline: 10.1380x; 1.0257x over previous
//
#include <hip/hip_runtime.h>

#define NELEM 21600
#define KSEL 1000
#define MAXB 18
#define NT 1024
#define CAP 2048
#define NBIN 6144
#define BSHIFT 12                   // bin width 4096 key-units: 6144 bins = 25.2M span
#define NCHUNK 4
#define QC 8100                     // float4s per K1 block (32400/4)
#define QK 5400                     // keys per K2 block (21600/4)
#define NFULL 21                    // fallback: 21*1024 = 21504
#define NTAIL (NELEM - NFULL * NT)  // 96

typedef unsigned long long ull;

// monotone map: ascending uint key <-> ascending float
__device__ __forceinline__ unsigned fkey(float f) {
  unsigned u = __float_as_uint(f);
  return (u & 0x80000000u) ? ~u : (u | 0x80000000u);
}
__device__ __forceinline__ float unfkey(unsigned k) {
  unsigned u = (k & 0x80000000u) ? (k ^ 0x80000000u) : ~k;
  return __uint_as_float(u);
}

// shared decode: idx -> (xc, yc, w, h)
__device__ __forceinline__ float4 decode_box(const float* xb, const float* anch,
                                             unsigned idx) {
  const float2* e2 = (const float2*)(xb + (size_t)idx * 6 + 2);
  float2 ra = e2[0], rb = e2[1];
  unsigned pp = (idx / 9u) % 60u;
  unsigned qq = idx / 540u;
  unsigned sr = idx % 9u;
  const float* ap = anch + (((pp * 40u + qq) * 9u + sr) * 4u);
  float ax = ap[0], ay = ap[1], aw = ap[2], ah = ap[3];
  float4 r;
  r.x = ra.x * aw + ax;          // xc
  r.y = ra.y * ah + ay;          // yc
  r.z = aw * expf(rb.x);         // w
  r.w = ah * expf(rb.y);         // h
  return r;
}

// ---------------- K1: full-chip float4 scan -> keys + chunk hists --------------
__global__ __launch_bounds__(NT) void k1_scan(
    const float* __restrict__ x, unsigned* __restrict__ gkeys,
    unsigned* __restrict__ ghist, unsigned* __restrict__ gcnt,
    unsigned* __restrict__ gflag) {
  const int blk = blockIdx.x;
  const int s = blk >> 2, c = blk & 3;
  const int t = threadIdx.x;
  const float4* xq = (const float4*)(x + (size_t)s * NELEM * 6);
  unsigned* gk = gkeys + (size_t)s * NELEM;

  __shared__ unsigned h[2048];
  h[2 * t] = 0u; h[2 * t + 1] = 0u;
  if (c == 0 && t == 0) { gcnt[s] = 0u; gflag[s] = 0u; }
  __syncthreads();

  const int base = c * QC;
  #pragma unroll
  for (int k = 0; k < 8; ++k) {
    int off = t + (k << 10);
    if (k < 7 || off < QC) {
      int g = base + off;
      float4 v = xq[g];
      int r = g % 3;
      if (r == 0) {
        unsigned key = fkey(v.x);
        gk[2 * (g / 3)] = key;
        atomicAdd(&h[key >> 21], 1u);
      } else if (r == 1) {
        unsigned key = fkey(v.z);
        gk[2 * (g / 3) + 1] = key;
        atomicAdd(&h[key >> 21], 1u);
      }
    }
  }
  __syncthreads();
  unsigned* gh = ghist + (size_t)blk * 2048;
  gh[2 * t] = h[2 * t];
  gh[2 * t + 1] = h[2 * t + 1];
}

// Wave-shuffle bucket select over hist[2048]. 16 waves x 128 buckets.
__device__ void select_bucket(const unsigned* hist, unsigned target,
                              volatile unsigned* chunkSuf,
                              unsigned* outB, unsigned* outCnt, unsigned* outAbove) {
  const int tid = threadIdx.x;
  const int w = tid >> 6, l = tid & 63;
  unsigned h1 = hist[w * 128 + 2 * l + 1];
  unsigned s = hist[w * 128 + 2 * l] + h1;
  #pragma unroll
  for (int d = 1; d < 64; d <<= 1) {
    unsigned t = __shfl_down(s, d);
    if (l + d < 64) s += t;
  }
  if (l == 0) chunkSuf[w] = s;
  __syncthreads();
  if (w == 0) {
    unsigned ct = (l < 16) ? chunkSuf[l] : 0u;
    unsigned cs = ct;
    #pragma unroll
    for (int d = 1; d < 16; d <<= 1) {
      unsigned t = __shfl_down(cs, d);
      if (l + d < 16) cs += t;
    }
    if (l < 16) chunkSuf[l] = cs - ct;
  }
  __syncthreads();
  unsigned base = chunkSuf[w];
  unsigned sufE = s + base;
  unsigned sN = __shfl_down(s, 1);
  unsigned sufN = ((l < 63) ? sN : 0u) + base;
  unsigned geOdd = sufN + h1;
  if (sufE >= target && geOdd < target) { *outB = w * 128u + 2u * l;     *outCnt = sufE;  *outAbove = geOdd; }
  if (geOdd >= target && sufN < target) { *outB = w * 128u + 2u * l + 1; *outCnt = geOdd; *outAbove = sufN;  }
  __syncthreads();
}

// ---------------- K2: full-chip threshold + compact + DECODE (4 blocks/sample) -
__global__ __launch_bounds__(NT) void k2_compact(
    const float* __restrict__ x, const float* __restrict__ anch,
    const unsigned* __restrict__ gkeys, const unsigned* __restrict__ ghist,
    ull* __restrict__ gselPk, float4* __restrict__ gbox,
    unsigned* __restrict__ gcnt, unsigned* __restrict__ gflag,
    unsigned* __restrict__ gtb) {
  const int blk = blockIdx.x;
  const int s = blk >> 2, q = blk & 3;
  const int tid = threadIdx.x;
  const float* xb = x + (size_t)s * NELEM * 6;

  __shared__ unsigned hist[2048];
  __shared__ unsigned chunkSuf[16];
  __shared__ ull lbuf[CAP];
  __shared__ unsigned lcnt, gbase;
  __shared__ unsigned sB, sCnt, sAbove;

  {
    unsigned h0 = 0, h1 = 0;
    #pragma unroll
    for (int c = 0; c < NCHUNK; ++c) {
      const unsigned* gh = ghist + (size_t)(s * NCHUNK + c) * 2048;
      h0 += gh[2 * tid];
      h1 += gh[2 * tid + 1];
    }
    hist[2 * tid] = h0; hist[2 * tid + 1] = h1;
  }
  if (tid == 0) lcnt = 0u;
  __syncthreads();
  select_bucket(hist, KSEL, chunkSuf, &sB, &sCnt, &sAbove);

  if (sCnt > (unsigned)CAP) {                 // astronomically rare tie storm
    if (tid == 0 && q == 0) gflag[s] = 1u;
    return;
  }
  const unsigned TB = sB << 21;
  if (tid == 0 && q == 0) gtb[s] = TB;
  const unsigned* ks = gkeys + (size_t)s * NELEM + q * QK;
  const int lw = tid & 63;
  #pragma unroll
  for (int it = 0; it < 6; ++it) {
    int i = tid + (it << 10);
    bool pred = false;
    unsigned k = 0u;
    if (i < QK) { k = ks[i]; pred = (k >= TB); }
    ull mask = __ballot(pred);
    if (mask) {
      int leader = __builtin_ctzll(mask);
      unsigned tot = (unsigned)__popcll(mask);
      unsigned bp = 0;
      if (lw == leader) bp = atomicAdd(&lcnt, tot);
      bp = __shfl(bp, leader);
      if (pred) {
        unsigned p = bp + (unsigned)__popcll(mask & ((1ull << lw) - 1ull));
        unsigned idx = (unsigned)(q * QK + i);
        lbuf[p] = ((ull)k << 32) | (unsigned)(~idx);
      }
    }
  }
  __syncthreads();
  if (tid == 0) gbase = atomicAdd(&gcnt[s], lcnt);
  __syncthreads();
  ull* gs = gselPk + (size_t)s * CAP;
  float4* gb = gbox + (size_t)s * CAP;
  const unsigned n = lcnt, b0 = gbase;
  for (unsigned i = tid; i < n; i += NT) {
    ull pk = lbuf[i];
    gs[b0 + i] = pk;
    gb[b0 + i] = decode_box(xb, anch, ~(unsigned)pk);   // full-chip gather
  }
}

// ---------------- K3: counting sort (slot payload) + LDS NMS + output ----------
__global__ __launch_bounds__(NT) void k3_final(
    const float* __restrict__ x, const float* __restrict__ anch,
    const unsigned* __restrict__ gkeys, const unsigned* __restrict__ ghist,
    const ull* __restrict__ gselPk, const float4* __restrict__ gbox,
    const unsigned* __restrict__ gcnt, const unsigned* __restrict__ gflag,
    const unsigned* __restrict__ gtb, float* __restrict__ out) {
  const int s = blockIdx.x;
  const int tid = threadIdx.x;
  const float* xb = x + (size_t)s * NELEM * 6;

  __shared__ ull pkraw[CAP];
  __shared__ ull sorted[CAP];
  __shared__ unsigned short slot16[CAP];
  __shared__ float4 boxL[CAP];                 // indexed by presort slot
  __shared__ unsigned hist[NBIN + 2];          // reused by fallback select
  __shared__ unsigned short orig16[NBIN + 2];
  __shared__ float px1[1088], py1[1088], px2[1088], py2[1088];
  __shared__ unsigned chunkSuf[16];
  __shared__ unsigned sB, sCnt, sAbove;
  __shared__ unsigned cntsh;
  __shared__ int keptRank[MAXB];
  __shared__ int numKept;

  unsigned n, TB;
  if (gflag[s] == 0u) {
    // ---- fast path: coalesced load of pre-compacted candidates + boxes ----
    n = gcnt[s]; if (n > CAP) n = CAP;
    TB = gtb[s];
    const ull* gs = gselPk + (size_t)s * CAP;
    const float4* gb = gbox + (size_t)s * CAP;
    for (unsigned i = tid; i < n; i += NT) {
      pkraw[i] = gs[i];
      boxL[i] = gb[i];
    }
  } else {
    // ---- rare fallback: in-block exact select (22-bit refine) + compact ----
    const unsigned* ks = gkeys + (size_t)s * NELEM;
    unsigned kv[NFULL];
    #pragma unroll
    for (int u = 0; u < NFULL; ++u) kv[u] = ks[tid + (u << 10)];
    unsigned ktail = 0u;
    const bool hastail = tid < NTAIL;
    if (hastail) ktail = ks[tid + NFULL * NT];
    {
      unsigned h0 = 0, h1 = 0;
      #pragma unroll
      for (int c = 0; c < NCHUNK; ++c) {
        const unsigned* gh = ghist + (size_t)(s * NCHUNK + c) * 2048;
        h0 += gh[2 * tid];
        h1 += gh[2 * tid + 1];
      }
      hist[2 * tid] = h0; hist[2 * tid + 1] = h1;
    }
    __syncthreads();
    select_bucket(hist, KSEL, chunkSuf, &sB, &sCnt, &sAbove);
    const unsigned b1 = sB, above1 = sAbove;
    hist[2 * tid] = 0u; hist[2 * tid + 1] = 0u;
    __syncthreads();
    #pragma unroll
    for (int u = 0; u < NFULL; ++u)
      if ((kv[u] >> 21) == b1) atomicAdd(&hist[(kv[u] >> 10) & 0x7FFu], 1u);
    if (hastail && (ktail >> 21) == b1) atomicAdd(&hist[(ktail >> 10) & 0x7FFu], 1u);
    __syncthreads();
    select_bucket(hist, KSEL - above1, chunkSuf, &sB, &sCnt, &sAbove);
    TB = (b1 << 21) | (sB << 10);
    if (tid == 0) cntsh = 0u;
    __syncthreads();
    const int lw = tid & 63;
    #pragma unroll
    for (int u = 0; u < NFULL; ++u) {
      bool pred = kv[u] >= TB;
      ull mask = __ballot(pred);
      if (mask) {
        int leader = __builtin_ctzll(mask);
        unsigned total = (unsigned)__popcll(mask);
        unsigned basep = 0;
        if (lw == leader) basep = atomicAdd(&cntsh, total);
        basep = __shfl(basep, leader);
        if (pred) {
          unsigned p = basep + (unsigned)__popcll(mask & ((1ull << lw) - 1ull));
          unsigned i = (unsigned)(tid + (u << 10));
          if (p < CAP) pkraw[p] = ((ull)kv[u] << 32) | (unsigned)(~i);
        }
      }
    }
    if (hastail && ktail >= TB) {
      unsigned p = atomicAdd(&cntsh, 1u);
      unsigned i = (unsigned)(tid + NFULL * NT);
      if (p < CAP) pkraw[p] = ((ull)ktail << 32) | (unsigned)(~i);
    }
    __syncthreads();
    n = (cntsh < CAP) ? cntsh : CAP;
    // decode in-block (rare)
    for (unsigned i = tid; i < n; i += NT)
      boxL[i] = decode_box(xb, anch, ~(unsigned)pkraw[i]);
  }

  // ---- counting sort with slot payload: bin by (key - TB) >> BSHIFT ----
  {
    #pragma unroll
    for (int j = 0; j < 6; ++j) hist[tid * 6 + j] = 0u;
    if (tid == 0) { hist[NBIN] = 0u; hist[NBIN + 1] = 0u; }
    __syncthreads();
    #pragma unroll
    for (int e0 = 0; e0 < 2; ++e0) {
      unsigned e = tid + (e0 << 10);
      if (e < n) {
        unsigned key = (unsigned)(pkraw[e] >> 32);
        unsigned bin = (key - TB) >> BSHIFT;
        if (bin > (NBIN - 1)) bin = NBIN - 1;
        atomicAdd(&hist[bin], 1u);
      }
    }
    __syncthreads();
    // suffix scan: suf[b] = sum_{b' >= b} cnt[b']
    unsigned c6[6];
    #pragma unroll
    for (int j = 0; j < 6; ++j) c6[j] = hist[tid * 6 + j];
    unsigned part = 0;
    #pragma unroll
    for (int j = 0; j < 6; ++j) part += c6[j];
    const int w = tid >> 6, l = tid & 63;
    unsigned ssum = part;
    #pragma unroll
    for (int d = 1; d < 64; d <<= 1) {
      unsigned t2 = __shfl_down(ssum, d);
      if (l + d < 64) ssum += t2;
    }
    if (l == 0) chunkSuf[w] = ssum;
    __syncthreads();
    if (w == 0) {
      unsigned ct = (l < 16) ? chunkSuf[l] : 0u;
      unsigned cs = ct;
      #pragma unroll
      for (int d = 1; d < 16; d <<= 1) {
        unsigned t2 = __shfl_down(cs, d);
        if (l + d < 16) cs += t2;
      }
      if (l < 16) chunkSuf[l] = cs - ct;
    }
    __syncthreads();
    unsigned after = chunkSuf[w] + (ssum - part);
    unsigned run = after;
    unsigned suf6[6];
    #pragma unroll
    for (int j = 5; j >= 0; --j) { run += c6[j]; suf6[j] = run; }
    __syncthreads();
    #pragma unroll
    for (int j = 0; j < 6; ++j) {
      hist[tid * 6 + j] = suf6[j];
      orig16[tid * 6 + j] = (unsigned short)suf6[j];
    }
    if (tid == 0) { hist[NBIN] = 0u; orig16[NBIN] = 0; }
    __syncthreads();
    // scatter with payload
    #pragma unroll
    for (int e0 = 0; e0 < 2; ++e0) {
      unsigned e = tid + (e0 << 10);
      if (e < n) {
        ull pk = pkraw[e];
        unsigned key = (unsigned)(pk >> 32);
        unsigned bin = (key - TB) >> BSHIFT;
        if (bin > (NBIN - 1)) bin = NBIN - 1;
        unsigned pos = atomicAdd(&hist[bin + 1], 1u);
        sorted[pos] = pk;
        slot16[pos] = (unsigned short)e;
      }
    }
    __syncthreads();
    // fixup: paired insertion sort within each bin segment
    #pragma unroll
    for (int b0 = 0; b0 < 6; ++b0) {
      int b = tid + (b0 << 10);
      if (b < NBIN) {
        int st = orig16[b + 1];
        int en = orig16[b];
        for (int i = st + 1; i < en; ++i) {
          ull v = sorted[i];
          unsigned short sv = slot16[i];
          int j = i - 1;
          while (j >= st && sorted[j] < v) {
            sorted[j + 1] = sorted[j];
            slot16[j + 1] = slot16[j];
            --j;
          }
          sorted[j + 1] = v;
          slot16[j + 1] = sv;
        }
      }
    }
    __syncthreads();
  }

  // ---- build stride-17 corner arrays from LDS boxes (no global reads) ----
  if (tid < KSEL) {
    float4 b = boxL[slot16[tid]];
    int a = (tid >> 4) * 17 + (tid & 15);
    px1[a] = b.x - 0.5f * b.z; px2[a] = b.x + 0.5f * b.z;
    py1[a] = b.y - 0.5f * b.w; py2[a] = b.y + 0.5f * b.w;
  }
  __syncthreads();

  // ---- ballot-NMS on wave 0: coords from LDS, tiny register state ----
  if (tid < 64) {
    const int lane = tid;
    unsigned alive = 0u;
    #pragma unroll
    for (int ss = 0; ss < 16; ++ss) {
      int r = lane * 16 + ss;
      alive |= (r < KSEL ? 1u : 0u) << ss;
    }
    int nk = 0;
    while (nk < MAXB) {
      ull bal = __ballot(alive != 0u);
      if (!bal) break;
      int F = __builtin_ctzll(bal);
      int myss = (int)__builtin_ctz(alive | 0x10000u);
      int ssw = __shfl(myss, F);
      int m = F * 16 + ssw;
      if (lane == 0) keptRank[nk] = m;
      int am = (m >> 4) * 17 + (m & 15);
      float wx1 = px1[am], wy1 = py1[am], wx2 = px2[am], wy2 = py2[am];
      ++nk;
      if (nk >= MAXB) break;
      #pragma unroll
      for (int ss = 0; ss < 16; ++ss) {
        if (alive & (1u << ss)) {
          int a = lane * 17 + ss;
          float x1 = px1[a], y1 = py1[a], x2 = px2[a], y2 = py2[a];
          float iw = fmaxf(fminf(x2, wx2) - fmaxf(x1, wx1), 0.f);
          float ih = fmaxf(fminf(y2, wy2) - fmaxf(y1, wy1), 0.f);
          float ar = (x2 - x1) * (y2 - y1);
          if (iw * ih / ar > 0.5f) alive &= ~(1u << ss);  // winner self-clears
        }
      }
    }
    if (lane == 0) numKept = nk;
  }
  __syncthreads();

  // ---- output: kept rows then pad rows cand[j - n]; all from LDS ----
  const int nK = numKept;
  if (tid < MAXB) {
    int j = tid;
    int r = (j < nK) ? keptRank[j] : (j - nK);
    ull pk = sorted[r];
    float4 b = boxL[slot16[r]];
    float sc = unfkey((unsigned)(pk >> 32));
    float* o = out + s * (MAXB * 5) + j * 5;
    o[0] = b.x; o[1] = b.y; o[2] = b.z; o[3] = b.w; o[4] = sc;
  }
}

extern "C" void kernel_launch(void* const* d_in, const int* in_sizes, int n_in,
                              void* d_out, int out_size, void* d_ws, size_t ws_size,
                              hipStream_t stream) {
  const float* x = (const float*)d_in[0];
  const float* anch = (const float*)d_in[1];
  float* out = (float*)d_out;
  const int B = in_sizes[0] / (NELEM * 6);
  ull* gselPk = (ull*)d_ws;                                 // B*2048 u64
  float4* gbox = (float4*)(gselPk + (size_t)B * CAP);       // B*2048 float4
  unsigned* ghist = (unsigned*)(gbox + (size_t)B * CAP);    // B*4*2048 u32
  unsigned* gkeys = ghist + (size_t)B * NCHUNK * 2048;      // B*21600 u32
  unsigned* gcnt = gkeys + (size_t)B * NELEM;               // B u32
  unsigned* gflag = gcnt + B;                               // B u32
  unsigned* gtb = gflag + B;                                // B u32
  k1_scan<<<dim3(B * NCHUNK), dim3(NT), 0, stream>>>(x, gkeys, ghist, gcnt, gflag);
  k2_compact<<<dim3(B * NCHUNK), dim3(NT), 0, stream>>>(x, anch, gkeys, ghist, gselPk, gbox, gcnt, gflag, gtb);
  k3_final<<<dim3(B), dim3(NT), 0, stream>>>(x, anch, gkeys, ghist, gselPk, gbox, gcnt, gflag, gtb, out);
}